// Round 1
// baseline (1380.154 us; speedup 1.0000x reference)
//
#include <hip/hip_runtime.h>
#include <math.h>

#define NHEADS 4
#define CIN 64
#define NT 256
#define NBLK 128   // blocks per batch for K1

// K1: fused kv-projection + exp + per-block partial context/sum accumulation.
// Grid: (NBLK, 2). Block: 256 threads, thread-per-position within a chunk.
__global__ __launch_bounds__(256) void lin_attn_ctx(
    const float* __restrict__ x, const float* __restrict__ Wqkv,
    float* __restrict__ P, int n, int nchunks)
{
    __shared__ float elds[NT * 32];
    __shared__ float vlds[NT * 32];
    const int tid = threadIdx.x;
    const int b = blockIdx.y;
    const int rt = tid >> 4, ct = tid & 15;
    const int d0 = rt * 2, e0 = ct * 2;

    float Cacc[NHEADS][2][2];
    float sacc[NHEADS][2];
#pragma unroll
    for (int h = 0; h < NHEADS; ++h) {
        sacc[h][0] = 0.f; sacc[h][1] = 0.f;
#pragma unroll
        for (int i = 0; i < 2; ++i)
#pragma unroll
            for (int j = 0; j < 2; ++j) Cacc[h][i][j] = 0.f;
    }

    const int swz = (tid & 7) << 2;  // word-index XOR swizzle (bank-conflict-free)

    for (int chunk = blockIdx.x; chunk < nchunks; chunk += gridDim.x) {
        const int p = chunk * NT + tid;
        const float* xb = x + (size_t)b * CIN * n + p;
        float xr[CIN];
#pragma unroll
        for (int c = 0; c < CIN; ++c) xr[c] = xb[(size_t)c * n];

#pragma unroll
        for (int h = 0; h < NHEADS; ++h) {
            const float* Wk = Wqkv + (size_t)(128 + h * 32) * CIN;
            const float* Wv = Wqkv + (size_t)(256 + h * 32) * CIN;
            // stage ek = exp(Wk @ x) for this thread's position (4 rows at a time)
#pragma unroll
            for (int q = 0; q < 8; ++q) {
                float a0 = 0.f, a1 = 0.f, a2 = 0.f, a3 = 0.f;
#pragma unroll
                for (int c = 0; c < CIN; ++c) {
                    const float xv = xr[c];
                    a0 += Wk[(4 * q + 0) * CIN + c] * xv;
                    a1 += Wk[(4 * q + 1) * CIN + c] * xv;
                    a2 += Wk[(4 * q + 2) * CIN + c] * xv;
                    a3 += Wk[(4 * q + 3) * CIN + c] * xv;
                }
                float4 ev;
                ev.x = __expf(a0); ev.y = __expf(a1);
                ev.z = __expf(a2); ev.w = __expf(a3);
                *reinterpret_cast<float4*>(&elds[tid * 32 + ((4 * q) ^ swz)]) = ev;
            }
            // stage v = Wv @ x
#pragma unroll
            for (int q = 0; q < 8; ++q) {
                float a0 = 0.f, a1 = 0.f, a2 = 0.f, a3 = 0.f;
#pragma unroll
                for (int c = 0; c < CIN; ++c) {
                    const float xv = xr[c];
                    a0 += Wv[(4 * q + 0) * CIN + c] * xv;
                    a1 += Wv[(4 * q + 1) * CIN + c] * xv;
                    a2 += Wv[(4 * q + 2) * CIN + c] * xv;
                    a3 += Wv[(4 * q + 3) * CIN + c] * xv;
                }
                float4 vv4; vv4.x = a0; vv4.y = a1; vv4.z = a2; vv4.w = a3;
                *reinterpret_cast<float4*>(&vlds[tid * 32 + ((4 * q) ^ swz)]) = vv4;
            }
            __syncthreads();
            // 2x2 register-tiled outer-product accumulation over the chunk
#pragma unroll 8
            for (int pp = 0; pp < NT; ++pp) {
                const int sp = (pp & 7) << 2;
                const float2 ev = *reinterpret_cast<const float2*>(&elds[pp * 32 + (d0 ^ sp)]);
                const float2 vv = *reinterpret_cast<const float2*>(&vlds[pp * 32 + (e0 ^ sp)]);
                Cacc[h][0][0] += ev.x * vv.x;
                Cacc[h][0][1] += ev.x * vv.y;
                Cacc[h][1][0] += ev.y * vv.x;
                Cacc[h][1][1] += ev.y * vv.y;
                if (ct == 0) { sacc[h][0] += ev.x; sacc[h][1] += ev.y; }
            }
            __syncthreads();
        }
    }

    float* Pb = P + ((size_t)(b * gridDim.x + blockIdx.x)) * 4224;
#pragma unroll
    for (int h = 0; h < NHEADS; ++h) {
#pragma unroll
        for (int i = 0; i < 2; ++i)
#pragma unroll
            for (int j = 0; j < 2; ++j)
                Pb[h * 1056 + (d0 + i) * 32 + (e0 + j)] = Cacc[h][i][j];
        if (ct == 0) {
            Pb[h * 1056 + 1024 + d0]     = sacc[h][0];
            Pb[h * 1056 + 1024 + d0 + 1] = sacc[h][1];
        }
    }
}

// K2: reduce per-block partials -> R[b][4224]
__global__ __launch_bounds__(256) void reduce_partials(
    const float* __restrict__ P, float* __restrict__ R, int nblk)
{
    const int b = blockIdx.y;
    const int idx = blockIdx.x * 256 + threadIdx.x;
    if (idx >= 4224) return;
    float acc = 0.f;
    for (int k = 0; k < nblk; ++k)
        acc += P[((size_t)(b * nblk + k)) * 4224 + idx];
    R[b * 4224 + idx] = acc;
}

// K3: build per-batch 64x64 matrix M = scale * W_out * blockdiag(ctx^T) * W_q
__global__ __launch_bounds__(256) void build_M(
    const float* __restrict__ R, const float* __restrict__ Wout,
    const float* __restrict__ Wqkv, float* __restrict__ Mws)
{
    __shared__ float ctx[4096];   // [h][d][e]
    __shared__ float Ash[8192];   // A[o][h*32+d]
    const int b = blockIdx.x;
    const int tid = threadIdx.x;
    for (int i = tid; i < 4096; i += 256) {
        const int h = i >> 10, r = i & 1023, d = r >> 5, e = r & 31;
        ctx[i] = R[b * 4224 + h * 1056 + d * 32 + e] /
                 R[b * 4224 + h * 1056 + 1024 + d];
    }
    __syncthreads();
    for (int i = tid; i < 8192; i += 256) {
        const int o = i >> 7, m = i & 127, h = m >> 5, d = m & 31;
        float acc = 0.f;
#pragma unroll
        for (int e = 0; e < 32; ++e)
            acc += Wout[o * 128 + h * 32 + e] * ctx[h * 1024 + d * 32 + e];
        Ash[i] = acc;
    }
    __syncthreads();
    const float scale = 0.17677669529663687f;  // 32^-0.5
    for (int i = tid; i < 4096; i += 256) {
        const int o = i >> 6, c = i & 63;
        float acc = 0.f;
#pragma unroll
        for (int m = 0; m < 128; ++m)
            acc += Ash[o * 128 + m] * Wqkv[m * 64 + c];
        Mws[b * 4096 + i] = acc * scale;
    }
}

// K4: y[b,o,p] = sum_c M_b[o,c] x[b,c,p] + b_out[o]
__global__ __launch_bounds__(256) void final_proj(
    const float* __restrict__ x, const float* __restrict__ Mws,
    const float* __restrict__ bout, float* __restrict__ y, int n)
{
    const int tid = threadIdx.x;
    const int b = blockIdx.y;
    const int p = blockIdx.x * NT + tid;
    const float* xb = x + (size_t)b * CIN * n + p;
    float xr[CIN];
#pragma unroll
    for (int c = 0; c < CIN; ++c) xr[c] = xb[(size_t)c * n];
    const float* M = Mws + b * 4096;
    float* yb = y + (size_t)b * CIN * n + p;
    for (int o = 0; o < CIN; ++o) {
        float acc = bout[o];
#pragma unroll
        for (int c = 0; c < CIN; ++c) acc += M[o * CIN + c] * xr[c];
        yb[(size_t)o * n] = acc;
    }
}

extern "C" void kernel_launch(void* const* d_in, const int* in_sizes, int n_in,
                              void* d_out, int out_size, void* d_ws, size_t ws_size,
                              hipStream_t stream) {
    const float* x    = (const float*)d_in[0];
    const float* Wqkv = (const float*)d_in[1];
    const float* Wout = (const float*)d_in[2];
    const float* bout = (const float*)d_in[3];
    float* y = (float*)d_out;

    const int n = in_sizes[0] / 128;   // b*c = 128 -> n = 110592
    const int nchunks = n / NT;        // 432

    float* P = (float*)d_ws;                       // 2*NBLK*4224 floats
    float* R = P + (size_t)2 * NBLK * 4224;        // 2*4224 floats
    float* M = R + (size_t)2 * 4224;               // 2*4096 floats

    lin_attn_ctx<<<dim3(NBLK, 2), 256, 0, stream>>>(x, Wqkv, P, n, nchunks);
    reduce_partials<<<dim3(17, 2), 256, 0, stream>>>(P, R, NBLK);
    build_M<<<2, 256, 0, stream>>>(R, Wout, Wqkv, M);
    final_proj<<<dim3(nchunks, 2), 256, 0, stream>>>(x, M, bout, y, n);
}

// Round 2
// 177.061 us; speedup vs baseline: 7.7948x; 7.7948x over previous
//
#include <hip/hip_runtime.h>
#include <math.h>

#define CIN 64
#define NP 128

typedef float f32x4 __attribute__((ext_vector_type(4)));
typedef short s16x8 __attribute__((ext_vector_type(8)));

union Pack { s16x8 v; uint4 q; unsigned short h[8]; };

static __device__ __forceinline__ unsigned short f2b(float f) {
    unsigned u = __builtin_bit_cast(unsigned, f);
    unsigned r = (u + 0x7FFFu + ((u >> 16) & 1u)) >> 16;   // RNE
    return (unsigned short)r;
}
static __device__ __forceinline__ float b2f(unsigned short h) {
    unsigned u = ((unsigned)h) << 16;
    return __builtin_bit_cast(float, u);
}

// K0: pack W_k, W_v (rows 128..383 of Wqkv) into bf16 MFMA A-fragment tiles.
// Tile t (16 rows), kc (K-half), lane l, elem j = W[128+t*16+(l&15)][kc*32+(l>>4)*8+j]
__global__ __launch_bounds__(256) void prep_w(const float* __restrict__ Wqkv,
                                              unsigned short* __restrict__ Wb) {
    int e0 = (blockIdx.x * 256 + threadIdx.x) * 8;   // < 16384
    int lane = (e0 >> 3) & 63;
    int kc = (e0 >> 9) & 1;
    int t = e0 >> 10;
    int row = 128 + t * 16 + (lane & 15);
    int c0 = kc * 32 + (lane >> 4) * 8;
    for (int j = 0; j < 8; ++j)
        Wb[e0 + j] = f2b(Wqkv[row * 64 + c0 + j]);
}

// K1: fused kv-projection (MFMA) + exp + context accumulation (MFMA).
__global__ __launch_bounds__(256, 2) void lin_attn_ctx(
    const float* __restrict__ x, const unsigned short* __restrict__ Wb,
    float* __restrict__ P, int n, int nch)
{
    __shared__ uint4 Xl4[1024];                           // 16 KiB: [pos 128][slot 8], swizzled
    __shared__ __align__(16) unsigned short EKVs[4][2560];// 20 KiB: per-wave EK | V (80B rows)

    const int tid = threadIdx.x;
    const int l = tid & 63;
    const int w = tid >> 6;
    const int b = blockIdx.y;
    const int l15 = l & 15, lg = l >> 4;
    const uint4* Wb4 = (const uint4*)Wb;

    f32x4 zero4 = {0.f, 0.f, 0.f, 0.f};
    f32x4 ctx[4][2][2];
    float sacc[4][2][4];
#pragma unroll
    for (int h = 0; h < 4; ++h)
#pragma unroll
        for (int a = 0; a < 2; ++a) {
#pragma unroll
            for (int c2 = 0; c2 < 2; ++c2) ctx[h][a][c2] = zero4;
#pragma unroll
            for (int r = 0; r < 4; ++r) sacc[h][a][r] = 0.f;
        }

    const size_t xbase = (size_t)b * CIN * n;

    for (int ch = blockIdx.x; ch < nch; ch += gridDim.x) {
        __syncthreads();
        // ---- stage X chunk (128 pos x 64 ch) -> bf16 LDS [pos][ch], 16B-slot XOR swizzle ----
        {
            const int prow = (tid & 63) * 2;
            const int chg = (tid >> 6) * 16;
            const float* xp = x + xbase + (size_t)chg * n + (size_t)ch * NP + prow;
            float2 v2[16];
#pragma unroll
            for (int c = 0; c < 16; ++c)
                v2[c] = *(const float2*)(xp + (size_t)c * n);
#pragma unroll
            for (int dp = 0; dp < 2; ++dp) {
#pragma unroll
                for (int s = 0; s < 2; ++s) {
                    Pack u;
#pragma unroll
                    for (int j = 0; j < 8; ++j)
                        u.h[j] = f2b(dp ? v2[s * 8 + j].y : v2[s * 8 + j].x);
                    int pos = prow + dp;
                    Xl4[pos * 8 + ((((tid >> 6) * 2 + s)) ^ ((pos >> 1) & 7))] = u.q;
                }
            }
        }
        __syncthreads();

        // ---- X B-fragments for this wave's 32 positions ----
        s16x8 bx[2][2];
#pragma unroll
        for (int pt = 0; pt < 2; ++pt)
#pragma unroll
            for (int kc = 0; kc < 2; ++kc) {
                int pos = w * 32 + pt * 16 + l15;
                bx[pt][kc] = *(const s16x8*)&Xl4[pos * 8 + ((kc * 4 + lg) ^ ((pos >> 1) & 7))];
            }

#pragma unroll
        for (int h = 0; h < 4; ++h) {
            // W A-fragments (L1-resident)
            s16x8 ak[2][2], av[2][2];
#pragma unroll
            for (int rt = 0; rt < 2; ++rt)
#pragma unroll
                for (int kc = 0; kc < 2; ++kc) {
                    ak[rt][kc] = *(const s16x8*)&Wb4[((2 * h + rt) * 2 + kc) * 64 + l];
                    av[rt][kc] = *(const s16x8*)&Wb4[((8 + 2 * h + rt) * 2 + kc) * 64 + l];
                }
            // projection: k and v, 32 rows x 32 pos, K=64
            f32x4 pk[2][2], pv[2][2];
#pragma unroll
            for (int rt = 0; rt < 2; ++rt)
#pragma unroll
                for (int pt = 0; pt < 2; ++pt) {
                    f32x4 z = zero4;
                    z = __builtin_amdgcn_mfma_f32_16x16x32_bf16(ak[rt][0], bx[pt][0], z, 0, 0, 0);
                    pk[rt][pt] = __builtin_amdgcn_mfma_f32_16x16x32_bf16(ak[rt][1], bx[pt][1], z, 0, 0, 0);
                    f32x4 z2 = zero4;
                    z2 = __builtin_amdgcn_mfma_f32_16x16x32_bf16(av[rt][0], bx[pt][0], z2, 0, 0, 0);
                    pv[rt][pt] = __builtin_amdgcn_mfma_f32_16x16x32_bf16(av[rt][1], bx[pt][1], z2, 0, 0, 0);
                }
            // exp + restage to per-wave [row][pos] (80B-padded rows)
#pragma unroll
            for (int rt = 0; rt < 2; ++rt)
#pragma unroll
                for (int pt = 0; pt < 2; ++pt)
#pragma unroll
                    for (int r = 0; r < 4; ++r) {
                        int row = rt * 16 + lg * 4 + r;
                        int pos = pt * 16 + l15;
                        float e = __expf(pk[rt][pt][r]);
                        unsigned short eb = f2b(e);
                        EKVs[w][row * 40 + pos] = eb;
                        sacc[h][rt][r] += b2f(eb);      // rounded value: consistent with numerator
                        EKVs[w][1280 + row * 40 + pos] = f2b(pv[rt][pt][r]);
                    }
            // context: C_h += EK (32xK32) @ V^T (K32x32)
            s16x8 ea[2], vbf[2];
#pragma unroll
            for (int kt = 0; kt < 2; ++kt)
                ea[kt] = *(const s16x8*)&EKVs[w][(kt * 16 + l15) * 40 + lg * 8];
#pragma unroll
            for (int vt = 0; vt < 2; ++vt)
                vbf[vt] = *(const s16x8*)&EKVs[w][1280 + (vt * 16 + l15) * 40 + lg * 8];
#pragma unroll
            for (int kt = 0; kt < 2; ++kt)
#pragma unroll
                for (int vt = 0; vt < 2; ++vt)
                    ctx[h][kt][vt] = __builtin_amdgcn_mfma_f32_16x16x32_bf16(
                        ea[kt], vbf[vt], ctx[h][kt][vt], 0, 0, 0);
        }
    }

    // ---- cross-wave reduce, write per-block partials ----
    float* Xf = (float*)Xl4;             // 4096 floats
    float* Sf = (float*)&EKVs[0][0];     // 128 floats
    float* Pb = P + (size_t)(b * gridDim.x + blockIdx.x) * 4224;
#pragma unroll
    for (int h = 0; h < 4; ++h) {
        __syncthreads();
#pragma unroll
        for (int kt = 0; kt < 2; ++kt)
#pragma unroll
            for (int vt = 0; vt < 2; ++vt)
#pragma unroll
                for (int r = 0; r < 4; ++r) {
                    int d = kt * 16 + lg * 4 + r, e = vt * 16 + l15;
                    Xf[w * 1024 + d * 32 + e] = ctx[h][kt][vt][r];
                }
#pragma unroll
        for (int rt = 0; rt < 2; ++rt)
#pragma unroll
            for (int r = 0; r < 4; ++r) {
                float s = sacc[h][rt][r];
                s += __shfl_xor(s, 1); s += __shfl_xor(s, 2);
                s += __shfl_xor(s, 4); s += __shfl_xor(s, 8);
                if (l15 == 0) Sf[w * 32 + rt * 16 + lg * 4 + r] = s;
            }
        __syncthreads();
        for (int i = tid; i < 1024; i += 256)
            Pb[h * 1056 + i] = Xf[i] + Xf[1024 + i] + Xf[2048 + i] + Xf[3072 + i];
        if (tid < 32)
            Pb[h * 1056 + 1024 + tid] = Sf[tid] + Sf[32 + tid] + Sf[64 + tid] + Sf[96 + tid];
    }
}

// K2: reduce per-block partials -> R[b][4224]
__global__ __launch_bounds__(256) void reduce_partials(
    const float* __restrict__ P, float* __restrict__ R, int nblk)
{
    const int b = blockIdx.y;
    const int idx = blockIdx.x * 256 + threadIdx.x;
    if (idx >= 4224) return;
    float acc = 0.f;
    for (int k = 0; k < nblk; ++k)
        acc += P[((size_t)(b * nblk + k)) * 4224 + idx];
    R[b * 4224 + idx] = acc;
}

// K3: build per-batch transposed 64x64 matrix Mt[c][o] = scale * (W_out blockdiag(ctx^T) W_q)[o][c]
__global__ __launch_bounds__(256) void build_M(
    const float* __restrict__ R, const float* __restrict__ Wout,
    const float* __restrict__ Wqkv, float* __restrict__ Mt)
{
    __shared__ float ctx[4096];
    __shared__ float Ash[8192];
    const int b = blockIdx.x;
    const int tid = threadIdx.x;
    for (int i = tid; i < 4096; i += 256) {
        const int h = i >> 10, rr = i & 1023, d = rr >> 5, e = rr & 31;
        ctx[i] = R[b * 4224 + h * 1056 + d * 32 + e] /
                 R[b * 4224 + h * 1056 + 1024 + d];
    }
    __syncthreads();
    for (int i = tid; i < 8192; i += 256) {
        const int o = i >> 7, m = i & 127, h = m >> 5, d = m & 31;
        float acc = 0.f;
#pragma unroll
        for (int e = 0; e < 32; ++e)
            acc += Wout[o * 128 + h * 32 + e] * ctx[h * 1024 + d * 32 + e];
        Ash[i] = acc;
    }
    __syncthreads();
    const float scale = 0.17677669529663687f;
    for (int i = tid; i < 4096; i += 256) {
        const int o = i >> 6, c = i & 63;
        float acc = 0.f;
#pragma unroll
        for (int m = 0; m < 128; ++m)
            acc += Ash[o * 128 + m] * Wqkv[m * 64 + c];
        Mt[b * 4096 + c * 64 + o] = acc * scale;   // transposed store
    }
}

// K4: y[b,o,p] = sum_c Mt[c][o] x[b,c,p] + b_out[o]  (c-outer, contiguous wave-uniform M rows)
__global__ __launch_bounds__(256, 4) void final_proj(
    const float* __restrict__ x, const float* __restrict__ Mt,
    const float* __restrict__ bout, float* __restrict__ y, int n)
{
    const int b = blockIdx.y;
    const int p = blockIdx.x * 256 + threadIdx.x;
    const float* xb = x + (size_t)b * CIN * n + p;
    const float* M = Mt + b * 4096;
    float acc[64];
#pragma unroll
    for (int o = 0; o < 64; ++o) acc[o] = bout[o];
    for (int c = 0; c < 64; ++c) {
        const float xv = xb[(size_t)c * n];
        const float* Mr = M + c * 64;
#pragma unroll
        for (int o = 0; o < 64; ++o) acc[o] += Mr[o] * xv;
    }
    float* yb = y + (size_t)b * CIN * n + p;
#pragma unroll
    for (int o = 0; o < 64; ++o) yb[(size_t)o * n] = acc[o];
}

extern "C" void kernel_launch(void* const* d_in, const int* in_sizes, int n_in,
                              void* d_out, int out_size, void* d_ws, size_t ws_size,
                              hipStream_t stream) {
    const float* x    = (const float*)d_in[0];
    const float* Wqkv = (const float*)d_in[1];
    const float* Wout = (const float*)d_in[2];
    const float* bout = (const float*)d_in[3];
    float* y = (float*)d_out;

    const int n = in_sizes[0] / 128;   // 110592
    const int nch = n / NP;            // 864

    // ws-adaptive partial-slot count
    int BLKX = 256;
    while (BLKX > 64) {
        size_t need = 32768 + (size_t)2 * BLKX * 4224 * 4 + 2 * 4224 * 4 + 2 * 4096 * 4;
        if (need <= ws_size) break;
        BLKX >>= 1;
    }
    unsigned short* Wb = (unsigned short*)d_ws;                  // 32 KiB
    float* P  = (float*)((char*)d_ws + 32768);
    float* R  = P + (size_t)2 * BLKX * 4224;
    float* Mt = R + 2 * 4224;

    prep_w<<<8, 256, 0, stream>>>(Wqkv, Wb);
    lin_attn_ctx<<<dim3(BLKX, 2), 256, 0, stream>>>(x, Wb, P, n, nch);
    reduce_partials<<<dim3(17, 2), 256, 0, stream>>>(P, R, BLKX);
    build_M<<<2, 256, 0, stream>>>(R, Wout, Wqkv, Mt);
    final_proj<<<dim3(n / 256, 2), 256, 0, stream>>>(x, Mt, bout, y, n);
}

// Round 5
// 157.836 us; speedup vs baseline: 8.7442x; 1.1218x over previous
//
#include <hip/hip_runtime.h>
#include <hip/hip_bf16.h>
#include <math.h>

#define CIN 64
#define NP 128

typedef float f32x4 __attribute__((ext_vector_type(4)));
typedef short s16x8 __attribute__((ext_vector_type(8)));

static __device__ __forceinline__ unsigned short f2b(float f) {
    unsigned u = __builtin_bit_cast(unsigned, f);
    unsigned r = (u + 0x7FFFu + ((u >> 16) & 1u)) >> 16;   // RNE
    return (unsigned short)r;
}
static __device__ __forceinline__ float b2f(unsigned short h) {
    unsigned u = ((unsigned)h) << 16;
    return __builtin_bit_cast(float, u);
}
// native packed f32x2 -> bf16x2 (compiler emits v_cvt_pk_bf16_f32)
static __device__ __forceinline__ unsigned pk2(float lo, float hi) {
    __hip_bfloat162 p = __float22bfloat162_rn(make_float2(lo, hi));
    unsigned r;
    __builtin_memcpy(&r, &p, 4);
    return r;
}

// K0: pack W_k, W_v (rows 128..383 of Wqkv) into bf16 MFMA A-fragment tiles.
__global__ __launch_bounds__(256) void prep_w(const float* __restrict__ Wqkv,
                                              unsigned short* __restrict__ Wb) {
    int e0 = (blockIdx.x * 256 + threadIdx.x) * 8;   // < 16384
    int lane = (e0 >> 3) & 63;
    int kc = (e0 >> 9) & 1;
    int t = e0 >> 10;
    int row = 128 + t * 16 + (lane & 15);
    int c0 = kc * 32 + (lane >> 4) * 8;
    for (int j = 0; j < 8; ++j)
        Wb[e0 + j] = f2b(Wqkv[row * 64 + c0 + j]);
}

// K1: fused kv-projection (MFMA) + exp + context accumulation (MFMA).
__global__ __launch_bounds__(256, 3) void lin_attn_ctx(
    const float* __restrict__ x, const unsigned short* __restrict__ Wb,
    float* __restrict__ P, int n, int nch)
{
    __shared__ uint4 Xl4[1024];                           // 16 KiB: [pos 128][slot 8], swizzled
    __shared__ __align__(16) unsigned short EKVs[4][2560];// 20 KiB: per-wave EK | V (80B rows)

    const int tid = threadIdx.x;
    const int l = tid & 63;
    const int w = tid >> 6;
    const int b = blockIdx.y;
    const int l15 = l & 15, lg = l >> 4;
    const uint4* Wb4 = (const uint4*)Wb;

    f32x4 zero4 = {0.f, 0.f, 0.f, 0.f};
    f32x4 ctx[4][2][2];
    float sacc[4][2][4];
#pragma unroll
    for (int h = 0; h < 4; ++h)
#pragma unroll
        for (int a = 0; a < 2; ++a) {
#pragma unroll
            for (int c2 = 0; c2 < 2; ++c2) ctx[h][a][c2] = zero4;
#pragma unroll
            for (int r = 0; r < 4; ++r) sacc[h][a][r] = 0.f;
        }

    const size_t xbase = (size_t)b * CIN * n;

    for (int ch = blockIdx.x; ch < nch; ch += gridDim.x) {
        __syncthreads();
        // ---- stage X chunk (128 pos x 64 ch) -> bf16 LDS [pos][ch], 16B-slot XOR swizzle ----
        {
            const int prow = (tid & 63) * 2;
            const int chg = (tid >> 6) * 16;
            const float* xp = x + xbase + (size_t)chg * n + (size_t)ch * NP + prow;
            float2 v2[16];
#pragma unroll
            for (int c = 0; c < 16; ++c)
                v2[c] = *(const float2*)(xp + (size_t)c * n);
#pragma unroll
            for (int dp = 0; dp < 2; ++dp) {
#pragma unroll
                for (int s = 0; s < 2; ++s) {
                    uint4 q;
                    q.x = pk2(dp ? v2[s*8+0].y : v2[s*8+0].x, dp ? v2[s*8+1].y : v2[s*8+1].x);
                    q.y = pk2(dp ? v2[s*8+2].y : v2[s*8+2].x, dp ? v2[s*8+3].y : v2[s*8+3].x);
                    q.z = pk2(dp ? v2[s*8+4].y : v2[s*8+4].x, dp ? v2[s*8+5].y : v2[s*8+5].x);
                    q.w = pk2(dp ? v2[s*8+6].y : v2[s*8+6].x, dp ? v2[s*8+7].y : v2[s*8+7].x);
                    int pos = prow + dp;
                    Xl4[pos * 8 + ((((tid >> 6) * 2 + s)) ^ ((pos >> 1) & 7))] = q;
                }
            }
        }
        __syncthreads();

        // ---- X B-fragments for this wave's 32 positions ----
        s16x8 bx[2][2];
#pragma unroll
        for (int pt = 0; pt < 2; ++pt)
#pragma unroll
            for (int kc = 0; kc < 2; ++kc) {
                int pos = w * 32 + pt * 16 + l15;
                bx[pt][kc] = *(const s16x8*)&Xl4[pos * 8 + ((kc * 4 + lg) ^ ((pos >> 1) & 7))];
            }

#pragma unroll
        for (int h = 0; h < 4; ++h) {
#pragma unroll
            for (int rt = 0; rt < 2; ++rt) {
                // W A-fragments (L1-resident)
                s16x8 ak0 = *(const s16x8*)&Wb4[((2 * h + rt) * 2 + 0) * 64 + l];
                s16x8 ak1 = *(const s16x8*)&Wb4[((2 * h + rt) * 2 + 1) * 64 + l];
                s16x8 av0 = *(const s16x8*)&Wb4[((8 + 2 * h + rt) * 2 + 0) * 64 + l];
                s16x8 av1 = *(const s16x8*)&Wb4[((8 + 2 * h + rt) * 2 + 1) * 64 + l];
#pragma unroll
                for (int pt = 0; pt < 2; ++pt) {
                    f32x4 z = zero4;
                    z = __builtin_amdgcn_mfma_f32_16x16x32_bf16(ak0, bx[pt][0], z, 0, 0, 0);
                    z = __builtin_amdgcn_mfma_f32_16x16x32_bf16(ak1, bx[pt][1], z, 0, 0, 0);
                    f32x4 z2 = zero4;
                    z2 = __builtin_amdgcn_mfma_f32_16x16x32_bf16(av0, bx[pt][0], z2, 0, 0, 0);
                    z2 = __builtin_amdgcn_mfma_f32_16x16x32_bf16(av1, bx[pt][1], z2, 0, 0, 0);
                    // exp + restage to per-wave [row][pos] (80B-padded rows)
                    const int row0 = rt * 16 + lg * 4;
                    const int pos = pt * 16 + l15;
                    {
                        float e0 = __expf(z[0]), e1 = __expf(z[1]);
                        float e2 = __expf(z[2]), e3 = __expf(z[3]);
                        unsigned a01 = pk2(e0, e1);
                        unsigned a23 = pk2(e2, e3);
                        unsigned short* bp = &EKVs[w][row0 * 40 + pos];
                        bp[0]   = (unsigned short)a01;
                        bp[40]  = (unsigned short)(a01 >> 16);
                        bp[80]  = (unsigned short)a23;
                        bp[120] = (unsigned short)(a23 >> 16);
                        // accumulate the ROUNDED values (consistent with numerator operand)
                        sacc[h][rt][0] += b2f((unsigned short)a01);
                        sacc[h][rt][1] += b2f((unsigned short)(a01 >> 16));
                        sacc[h][rt][2] += b2f((unsigned short)a23);
                        sacc[h][rt][3] += b2f((unsigned short)(a23 >> 16));
                    }
                    {
                        unsigned a01 = pk2(z2[0], z2[1]);
                        unsigned a23 = pk2(z2[2], z2[3]);
                        unsigned short* bp = &EKVs[w][1280 + row0 * 40 + pos];
                        bp[0]   = (unsigned short)a01;
                        bp[40]  = (unsigned short)(a01 >> 16);
                        bp[80]  = (unsigned short)a23;
                        bp[120] = (unsigned short)(a23 >> 16);
                    }
                }
            }
            // context: C_h += EK (32xK32) @ V^T (K32x32)
            s16x8 ea[2], vbf[2];
#pragma unroll
            for (int kt = 0; kt < 2; ++kt)
                ea[kt] = *(const s16x8*)&EKVs[w][(kt * 16 + l15) * 40 + lg * 8];
#pragma unroll
            for (int vt = 0; vt < 2; ++vt)
                vbf[vt] = *(const s16x8*)&EKVs[w][1280 + (vt * 16 + l15) * 40 + lg * 8];
#pragma unroll
            for (int kt = 0; kt < 2; ++kt)
#pragma unroll
                for (int vt = 0; vt < 2; ++vt)
                    ctx[h][kt][vt] = __builtin_amdgcn_mfma_f32_16x16x32_bf16(
                        ea[kt], vbf[vt], ctx[h][kt][vt], 0, 0, 0);
        }
    }

    // ---- cross-wave reduce, write per-block partials ----
    float* Xf = (float*)Xl4;             // 4096 floats
    float* Sf = (float*)&EKVs[0][0];     // 128 floats
    float* Pb = P + (size_t)(b * gridDim.x + blockIdx.x) * 4224;
#pragma unroll
    for (int h = 0; h < 4; ++h) {
        __syncthreads();
#pragma unroll
        for (int kt = 0; kt < 2; ++kt)
#pragma unroll
            for (int vt = 0; vt < 2; ++vt)
#pragma unroll
                for (int r = 0; r < 4; ++r) {
                    int d = kt * 16 + lg * 4 + r, e = vt * 16 + l15;
                    Xf[w * 1024 + d * 32 + e] = ctx[h][kt][vt][r];
                }
#pragma unroll
        for (int rt = 0; rt < 2; ++rt)
#pragma unroll
            for (int r = 0; r < 4; ++r) {
                float s = sacc[h][rt][r];
                s += __shfl_xor(s, 1); s += __shfl_xor(s, 2);
                s += __shfl_xor(s, 4); s += __shfl_xor(s, 8);
                if (l15 == 0) Sf[w * 32 + rt * 16 + lg * 4 + r] = s;
            }
        __syncthreads();
        for (int i = tid; i < 1024; i += 256)
            Pb[h * 1056 + i] = Xf[i] + Xf[1024 + i] + Xf[2048 + i] + Xf[3072 + i];
        if (tid < 32)
            Pb[h * 1056 + 1024 + tid] = Sf[tid] + Sf[32 + tid] + Sf[64 + tid] + Sf[96 + tid];
    }
}

// K2a: slot-sliced partial reduce: P[b][slot][4224] -> P2[b][16][4224]
__global__ __launch_bounds__(256) void reduce_p1(
    const float* __restrict__ P, float* __restrict__ P2, int nblk)
{
    const int idx = blockIdx.x * 256 + threadIdx.x;
    if (idx >= 4224) return;
    const int b = blockIdx.z, sz = blockIdx.y;
    float acc = 0.f;
    for (int slot = sz; slot < nblk; slot += 16)
        acc += P[((size_t)(b * nblk + slot)) * 4224 + idx];
    P2[((size_t)(b * 16 + sz)) * 4224 + idx] = acc;
}

// K2b: final reduce -> R[b][4224]
__global__ __launch_bounds__(256) void reduce_p2(
    const float* __restrict__ P2, float* __restrict__ R)
{
    const int idx = blockIdx.x * 256 + threadIdx.x;
    if (idx >= 4224) return;
    const int b = blockIdx.y;
    float acc = 0.f;
#pragma unroll
    for (int s = 0; s < 16; ++s)
        acc += P2[((size_t)(b * 16 + s)) * 4224 + idx];
    R[b * 4224 + idx] = acc;
}

// K3: build per-batch transposed 64x64 matrix Mt[c][o]
__global__ __launch_bounds__(256) void build_M(
    const float* __restrict__ R, const float* __restrict__ Wout,
    const float* __restrict__ Wqkv, float* __restrict__ Mt)
{
    __shared__ float ctx[4096];
    __shared__ float Ash[8192];
    const int b = blockIdx.x;
    const int tid = threadIdx.x;
    for (int i = tid; i < 4096; i += 256) {
        const int h = i >> 10, rr = i & 1023, d = rr >> 5, e = rr & 31;
        ctx[i] = R[b * 4224 + h * 1056 + d * 32 + e] /
                 R[b * 4224 + h * 1056 + 1024 + d];
    }
    __syncthreads();
    for (int i = tid; i < 8192; i += 256) {
        const int o = i >> 7, m = i & 127, h = m >> 5, d = m & 31;
        float acc = 0.f;
#pragma unroll
        for (int e = 0; e < 32; ++e)
            acc += Wout[o * 128 + h * 32 + e] * ctx[h * 1024 + d * 32 + e];
        Ash[i] = acc;
    }
    __syncthreads();
    const float scale = 0.17677669529663687f;
    for (int i = tid; i < 4096; i += 256) {
        const int o = i >> 6, c = i & 63;
        float acc = 0.f;
#pragma unroll
        for (int m = 0; m < 128; ++m)
            acc += Ash[o * 128 + m] * Wqkv[m * 64 + c];
        Mt[b * 4096 + c * 64 + o] = acc * scale;   // transposed store
    }
}

// K4: y[b,o,p] = sum_c Mt[c][o] x[b,c,p] + b_out[o]
__global__ __launch_bounds__(256, 4) void final_proj(
    const float* __restrict__ x, const float* __restrict__ Mt,
    const float* __restrict__ bout, float* __restrict__ y, int n)
{
    const int b = blockIdx.y;
    const int p = blockIdx.x * 256 + threadIdx.x;
    const float* xb = x + (size_t)b * CIN * n + p;
    const float* M = Mt + b * 4096;
    float acc[64];
#pragma unroll
    for (int o = 0; o < 64; ++o) acc[o] = bout[o];
    for (int c = 0; c < 64; ++c) {
        const float xv = xb[(size_t)c * n];
        const float* Mr = M + c * 64;
#pragma unroll
        for (int o = 0; o < 64; ++o) acc[o] += Mr[o] * xv;
    }
    float* yb = y + (size_t)b * CIN * n + p;
#pragma unroll
    for (int o = 0; o < 64; ++o) yb[(size_t)o * n] = acc[o];
}

extern "C" void kernel_launch(void* const* d_in, const int* in_sizes, int n_in,
                              void* d_out, int out_size, void* d_ws, size_t ws_size,
                              hipStream_t stream) {
    const float* x    = (const float*)d_in[0];
    const float* Wqkv = (const float*)d_in[1];
    const float* Wout = (const float*)d_in[2];
    const float* bout = (const float*)d_in[3];
    float* y = (float*)d_out;

    const int n = in_sizes[0] / 128;   // 110592
    const int nch = n / NP;            // 864

    // ws-adaptive partial-slot count
    int BLKX = 432;
    for (;;) {
        size_t need = 32768 + (size_t)2 * BLKX * 4224 * 4   // P
                    + (size_t)2 * 16 * 4224 * 4             // P2
                    + 2 * 4224 * 4 + 2 * 4096 * 4;          // R, Mt
        if (need <= ws_size || BLKX <= 64) break;
        BLKX = (BLKX == 432) ? 256 : (BLKX >> 1);
    }
    unsigned short* Wb = (unsigned short*)d_ws;                  // 32 KiB
    float* P  = (float*)((char*)d_ws + 32768);
    float* P2 = P + (size_t)2 * BLKX * 4224;
    float* R  = P2 + (size_t)2 * 16 * 4224;
    float* Mt = R + 2 * 4224;

    prep_w<<<8, 256, 0, stream>>>(Wqkv, Wb);
    lin_attn_ctx<<<dim3(BLKX, 2), 256, 0, stream>>>(x, Wb, P, n, nch);
    reduce_p1<<<dim3(17, 16, 2), 256, 0, stream>>>(P, P2, BLKX);
    reduce_p2<<<dim3(17, 2), 256, 0, stream>>>(P2, R);
    build_M<<<2, 256, 0, stream>>>(R, Wout, Wqkv, Mt);
    final_proj<<<dim3(n / 256, 2), 256, 0, stream>>>(x, Mt, bout, y, n);
}